// Round 7
// baseline (144.593 us; speedup 1.0000x reference)
//
#include <hip/hip_runtime.h>
#include <hip/hip_fp16.h>

#define BATCH 32
#define TLEN  4096
#define CH    128      // C == F == 128
#define KW    3
#define DIL   8

#define BM    128                // output rows per block
#define HR    (BM + 2 * DIL)     // 144  h rows needed
#define WROWS (BM + 4 * DIL)     // 160  x rows needed
#define LDSC  136                // padded row len (f16): 272B stride, 16B-aligned,
                                 // stride%32banks==4 dwords -> worst 2-way (free)

typedef _Float16 f16x8 __attribute__((ext_vector_type(8)));
typedef float    f32x4 __attribute__((ext_vector_type(4)));

// ---------------------------------------------------------------------------
// Prep: Wt[j][f][c] = (f16) W[c][j][f]   for both layers' kernels.
// W is (C, K, F) row-major: W[c*KW*CH + j*CH + f].
// ---------------------------------------------------------------------------
__global__ void prep_weights_kernel(const float* __restrict__ W1,
                                    const float* __restrict__ W2,
                                    _Float16* __restrict__ Wt1,
                                    _Float16* __restrict__ Wt2) {
    const int total = KW * CH * CH;
    int idx = blockIdx.x * 256 + threadIdx.x;
    if (idx >= 2 * total) return;
    const float* W  = (idx < total) ? W1 : W2;
    _Float16*    Wt = (idx < total) ? Wt1 : Wt2;
    int r = idx % total;
    int j = r / (CH * CH);
    int f = (r / CH) % CH;
    int c = r % CH;
    Wt[j * CH * CH + f * CH + c] = (_Float16)W[c * (KW * CH) + j * CH + f];
}

// ---------------------------------------------------------------------------
// Fused TemporalDeConvBlock, BM=128: one 160-row x window staged once, G1 is
// a single 108-MFMA burst per wave, h (144 rows) overwrites the dead x
// window, G2 = 96 MFMA, residual re-read from global x. 512 thr = 8 waves,
// wave w owns cols [16w,16w+16); per-layer weight slice in regs (48 VGPR).
// Barrier density halved vs BM=64 (3 barriers / 128 rows) — attacks the
// barrier-parking that keeps all pipes <20% busy.
// __launch_bounds__(512,4): VGPR cap 128 — peak live ~110 audited. Lowering
// the cap spilled catastrophically twice (r3: (256,3)+192R live; r5:
// (512,6)=85-cap). DO NOT lower.
// ---------------------------------------------------------------------------
__global__ __launch_bounds__(512, 4)
void fused_deconv_kernel(const float* __restrict__ x,
                         const _Float16* __restrict__ Wt1,
                         const float* __restrict__ bias1,
                         const _Float16* __restrict__ Wt2,
                         const float* __restrict__ bias2,
                         float* __restrict__ out)
{
    __shared__ __align__(16) _Float16 buf[WROWS][LDSC];   // 160*136*2 = 43520 B

    const int tid  = threadIdx.x;
    const int lane = tid & 63;
    const int wid  = tid >> 6;         // 0..7
    const int l15  = lane & 15;
    const int kg   = lane >> 4;        // 0..3
    const int nc   = wid << 4;         // wave column base: 0,16,...,112

    const int bt = blockIdx.x;
    const int b  = bt >> 5;            // TLEN/BM = 32 tiles per batch
    const int t0 = (bt & 31) << 7;

    // ---- prefetch GEMM1 weight fragments (12 x 16B = 48 VGPRs); L2 latency
    // overlaps the x staging below.
    f16x8 w1[12];
#pragma unroll
    for (int ks = 0; ks < 12; ++ks) {
        const int j  = ks >> 2;
        const int c0 = (ks & 3) << 5;
        w1[ks] = *(const f16x8*)(Wt1 + (size_t)j * (CH * CH)
                                 + (nc + l15) * CH + c0 + kg * 8);
    }

    // ---- stage x window (f32 -> f16), rows t0..t0+159, zero past TLEN.
    // Two-phase: issue all 10 global loads, then convert+write (deep MLP).
    f32x4 va[5][2];
#pragma unroll
    for (int p = 0; p < 5; ++p) {
        const int i   = tid + 512 * p;
        const int row = i >> 4;
        const int c8  = (i & 15) << 3;
        const int t   = t0 + row;
        if (t < TLEN) {
            const float* xp = x + ((size_t)b * TLEN + t) * CH + c8;
            va[p][0] = *(const f32x4*)(xp + 0);
            va[p][1] = *(const f32x4*)(xp + 4);
        } else {
            va[p][0] = (f32x4){0.f, 0.f, 0.f, 0.f};
            va[p][1] = (f32x4){0.f, 0.f, 0.f, 0.f};
        }
    }
#pragma unroll
    for (int p = 0; p < 5; ++p) {
        const int i   = tid + 512 * p;
        const int row = i >> 4;
        const int c8  = (i & 15) << 3;
        f16x8 o;
        o[0] = (_Float16)va[p][0][0]; o[1] = (_Float16)va[p][0][1];
        o[2] = (_Float16)va[p][0][2]; o[3] = (_Float16)va[p][0][3];
        o[4] = (_Float16)va[p][1][0]; o[5] = (_Float16)va[p][1][1];
        o[6] = (_Float16)va[p][1][2]; o[7] = (_Float16)va[p][1][3];
        *(f16x8*)&buf[row][c8] = o;
    }

    const float bv1 = 128.0f * bias1[nc + l15];
    const float bv2 = 128.0f * bias2[nc + l15];

    __syncthreads();

    // ---- GEMM1: h rows 0..143, cols [nc,nc+16) — 108 MFMA uninterrupted
    f32x4 acc1[9];
#pragma unroll
    for (int m = 0; m < 9; ++m) acc1[m] = (f32x4){0.f, 0.f, 0.f, 0.f};
#pragma unroll
    for (int ks = 0; ks < 12; ++ks) {
        const int j     = ks >> 2;
        const int c0    = (ks & 3) << 5;
        const int shift = (2 - j) * DIL;
#pragma unroll
        for (int m = 0; m < 9; ++m) {
            f16x8 af = *(const f16x8*)&buf[m * 16 + shift + l15][c0 + kg * 8];
            acc1[m] = __builtin_amdgcn_mfma_f32_16x16x32_f16(af, w1[ks], acc1[m], 0, 0, 0);
        }
    }

    // ---- prefetch GEMM2 weights (w1 dead, regs recycle); latency hides
    // under the barrier + h-store below.
    f16x8 w2[12];
#pragma unroll
    for (int ks = 0; ks < 12; ++ks) {
        const int j  = ks >> 2;
        const int c0 = (ks & 3) << 5;
        w2[ks] = *(const f16x8*)(Wt2 + (size_t)j * (CH * CH)
                                 + (nc + l15) * CH + c0 + kg * 8);
    }

    // all waves done READING the x window before h overwrites it
    __syncthreads();

    // ---- store h rows 0..143 into the SAME buffer (relu + bias)
    {
        const int f = nc + l15;
#pragma unroll
        for (int m = 0; m < 9; ++m) {
#pragma unroll
            for (int i = 0; i < 4; ++i) {
                const int r = m * 16 + kg * 4 + i;
                const int u = t0 + r;
                const int nv = 1 + (u < TLEN - DIL) + (u < TLEN - 2 * DIL);
                float v = acc1[m][i] + (float)nv * bv1;
                v = fmaxf(v, 0.0f);
                buf[r][f] = (u < TLEN) ? (_Float16)v : (_Float16)0.0f;
            }
        }
    }
    __syncthreads();

    // ---- GEMM2: out rows 0..127, cols [nc,nc+16) — 96 MFMA
    f32x4 acc2[8];
#pragma unroll
    for (int m = 0; m < 8; ++m) acc2[m] = (f32x4){0.f, 0.f, 0.f, 0.f};
#pragma unroll
    for (int ks = 0; ks < 12; ++ks) {
        const int j     = ks >> 2;
        const int c0    = (ks & 3) << 5;
        const int shift = (2 - j) * DIL;
#pragma unroll
        for (int m = 0; m < 8; ++m) {
            f16x8 af = *(const f16x8*)&buf[m * 16 + shift + l15][c0 + kg * 8];
            acc2[m] = __builtin_amdgcn_mfma_f32_16x16x32_f16(af, w2[ks], acc2[m], 0, 0, 0);
        }
    }

    // ---- epilogue: bias2 + relu, + residual (f32 x from global), relu, store
    {
        const int f = nc + l15;
#pragma unroll
        for (int m = 0; m < 8; ++m) {
#pragma unroll
            for (int i = 0; i < 4; ++i) {
                const int r = m * 16 + kg * 4 + i;
                const int t = t0 + r;
                const int nv = 1 + (t < TLEN - DIL) + (t < TLEN - 2 * DIL);
                float v = acc2[m][i] + (float)nv * bv2;
                v = fmaxf(v, 0.0f);
                const size_t gi = ((size_t)b * TLEN + t) * CH + f;
                v = v + x[gi];
                v = fmaxf(v, 0.0f);
                out[gi] = v;
            }
        }
    }
}

// ---------------------------------------------------------------------------
extern "C" void kernel_launch(void* const* d_in, const int* in_sizes, int n_in,
                              void* d_out, int out_size, void* d_ws, size_t ws_size,
                              hipStream_t stream) {
    const float* x  = (const float*)d_in[0];
    const float* W1 = (const float*)d_in[1];
    const float* b1 = (const float*)d_in[2];
    const float* W2 = (const float*)d_in[3];
    const float* b2 = (const float*)d_in[4];
    float* out = (float*)d_out;

    // workspace: Wt1 (3*128*128 f16) | Wt2
    _Float16* Wt1 = (_Float16*)d_ws;
    _Float16* Wt2 = Wt1 + KW * CH * CH;

    prep_weights_kernel<<<(2 * KW * CH * CH + 255) / 256, 256, 0, stream>>>(W1, W2, Wt1, Wt2);

    const int grid = BATCH * (TLEN / BM);   // 1024 blocks
    fused_deconv_kernel<<<grid, 512, 0, stream>>>(x, Wt1, b1, Wt2, b2, out);
}

// Round 8
// 70.305 us; speedup vs baseline: 2.0567x; 2.0567x over previous
//
#include <hip/hip_runtime.h>
#include <hip/hip_fp16.h>

#define BATCH 32
#define TLEN  4096
#define CH    128      // C == F == 128
#define KW    3
#define DIL   8

#define BM    128                // output rows per block
#define HR    (BM + 2 * DIL)     // 144  h rows needed
#define WROWS (BM + 4 * DIL)     // 160  x rows needed
#define LDSC  136                // padded row len (f16): 272B stride, 16B-aligned,
                                 // stride%128B==16B -> worst 2-way bank alias (free, m136)

typedef _Float16 f16x8 __attribute__((ext_vector_type(8)));
typedef float    f32x4 __attribute__((ext_vector_type(4)));

// ---------------------------------------------------------------------------
// Prep: Wt[j][f][c] = (f16) W[c][j][f]   for both layers' kernels.
// W is (C, K, F) row-major: W[c*KW*CH + j*CH + f].
// ---------------------------------------------------------------------------
__global__ void prep_weights_kernel(const float* __restrict__ W1,
                                    const float* __restrict__ W2,
                                    _Float16* __restrict__ Wt1,
                                    _Float16* __restrict__ Wt2) {
    const int total = KW * CH * CH;
    int idx = blockIdx.x * 256 + threadIdx.x;
    if (idx >= 2 * total) return;
    const float* W  = (idx < total) ? W1 : W2;
    _Float16*    Wt = (idx < total) ? Wt1 : Wt2;
    int r = idx % total;
    int j = r / (CH * CH);
    int f = (r / CH) % CH;
    int c = r % CH;
    Wt[j * CH * CH + f * CH + c] = (_Float16)W[c * (KW * CH) + j * CH + f];
}

// ---------------------------------------------------------------------------
// Fused TemporalDeConvBlock. 256 threads = 4 waves; wave w owns cols
// [32w, 32w+32) as TWO 16-col sub-tiles -> each A-fragment ds_read feeds
// 2 MFMA (halves LDS read traffic vs 16-col waves). BM=128: one 160-row
// x window staged once; h (144 rows) overwrites the dead x window;
// residual re-read from global x (L2/L3-resident).
// VGPR budget: 256-thread block, NO waves-per-EU bound (cap 256).
//   peak live ~190 = w[12][2] 96 + acc1[9][2] 72 + temps.
//   LESSONS: (256,3)/(512,6) caps spilled (r3/r5); 512-thread blocks are
//   pinned to 64 VGPRs by the allocator regardless of bounds (r4/r6/r7).
// ---------------------------------------------------------------------------
__global__ __launch_bounds__(256)
void fused_deconv_kernel(const float* __restrict__ x,
                         const _Float16* __restrict__ Wt1,
                         const float* __restrict__ bias1,
                         const _Float16* __restrict__ Wt2,
                         const float* __restrict__ bias2,
                         float* __restrict__ out)
{
    __shared__ __align__(16) _Float16 buf[WROWS][LDSC];   // 160*136*2 = 43520 B

    const int tid  = threadIdx.x;
    const int lane = tid & 63;
    const int wid  = tid >> 6;         // 0..3
    const int l15  = lane & 15;
    const int kg   = lane >> 4;        // 0..3
    const int nc   = wid << 5;         // wave column base: 0,32,64,96

    const int bt = blockIdx.x;
    const int b  = bt >> 5;            // TLEN/BM = 32 tiles per batch
    const int t0 = (bt & 31) << 7;

    // ---- prefetch GEMM1 weight fragments (24 x 16B = 96 VGPRs); L2 latency
    // overlaps the x staging below.
    f16x8 w1[12][2];
#pragma unroll
    for (int ks = 0; ks < 12; ++ks) {
        const int j  = ks >> 2;
        const int c0 = (ks & 3) << 5;
        const _Float16* wb = Wt1 + (size_t)j * (CH * CH) + c0 + kg * 8;
        w1[ks][0] = *(const f16x8*)(wb + (nc + l15) * CH);
        w1[ks][1] = *(const f16x8*)(wb + (nc + 16 + l15) * CH);
    }

    // ---- stage x window (f32 -> f16), rows t0..t0+159, zero past TLEN.
    // Streaming convert (low register footprint; compiler pipelines).
#pragma unroll
    for (int p = 0; p < 10; ++p) {
        const int i   = tid + 256 * p;
        const int row = i >> 4;
        const int c8  = (i & 15) << 3;
        const int t   = t0 + row;
        f16x8 o;
        if (t < TLEN) {
            const float* xp = x + ((size_t)b * TLEN + t) * CH + c8;
            f32x4 v0 = *(const f32x4*)(xp + 0);
            f32x4 v1 = *(const f32x4*)(xp + 4);
            o[0] = (_Float16)v0[0]; o[1] = (_Float16)v0[1];
            o[2] = (_Float16)v0[2]; o[3] = (_Float16)v0[3];
            o[4] = (_Float16)v1[0]; o[5] = (_Float16)v1[1];
            o[6] = (_Float16)v1[2]; o[7] = (_Float16)v1[3];
        } else {
            o = (f16x8){};
        }
        *(f16x8*)&buf[row][c8] = o;
    }

    const float bv1_0 = 128.0f * bias1[nc + l15];
    const float bv1_1 = 128.0f * bias1[nc + 16 + l15];
    const float bv2_0 = 128.0f * bias2[nc + l15];
    const float bv2_1 = 128.0f * bias2[nc + 16 + l15];

    __syncthreads();

    // ---- GEMM1: h rows 0..143, cols [nc,nc+32) — 216 MFMA / 108 ds_read
    f32x4 acc1[9][2];
#pragma unroll
    for (int m = 0; m < 9; ++m) {
        acc1[m][0] = (f32x4){0.f, 0.f, 0.f, 0.f};
        acc1[m][1] = (f32x4){0.f, 0.f, 0.f, 0.f};
    }
#pragma unroll
    for (int ks = 0; ks < 12; ++ks) {
        const int j     = ks >> 2;
        const int c0    = (ks & 3) << 5;
        const int shift = (2 - j) * DIL;
#pragma unroll
        for (int m = 0; m < 9; ++m) {
            f16x8 af = *(const f16x8*)&buf[m * 16 + shift + l15][c0 + kg * 8];
            acc1[m][0] = __builtin_amdgcn_mfma_f32_16x16x32_f16(af, w1[ks][0], acc1[m][0], 0, 0, 0);
            acc1[m][1] = __builtin_amdgcn_mfma_f32_16x16x32_f16(af, w1[ks][1], acc1[m][1], 0, 0, 0);
        }
    }

    // ---- prefetch GEMM2 weights (w1 dead, regs recycle); latency hides
    // under the barrier + h-store below.
    f16x8 w2[12][2];
#pragma unroll
    for (int ks = 0; ks < 12; ++ks) {
        const int j  = ks >> 2;
        const int c0 = (ks & 3) << 5;
        const _Float16* wb = Wt2 + (size_t)j * (CH * CH) + c0 + kg * 8;
        w2[ks][0] = *(const f16x8*)(wb + (nc + l15) * CH);
        w2[ks][1] = *(const f16x8*)(wb + (nc + 16 + l15) * CH);
    }

    // all waves done READING the x window before h overwrites it
    __syncthreads();

    // ---- store h rows 0..143 into the SAME buffer (relu + bias)
#pragma unroll
    for (int m = 0; m < 9; ++m) {
#pragma unroll
        for (int nn = 0; nn < 2; ++nn) {
            const float bv = nn ? bv1_1 : bv1_0;
            const int f = nc + nn * 16 + l15;
#pragma unroll
            for (int i = 0; i < 4; ++i) {
                const int r = m * 16 + kg * 4 + i;
                const int u = t0 + r;
                const int nv = 1 + (u < TLEN - DIL) + (u < TLEN - 2 * DIL);
                float v = acc1[m][nn][i] + (float)nv * bv;
                v = fmaxf(v, 0.0f);
                buf[r][f] = (u < TLEN) ? (_Float16)v : (_Float16)0.0f;
            }
        }
    }
    __syncthreads();

    // ---- GEMM2: out rows 0..127, cols [nc,nc+32) — 192 MFMA / 96 ds_read
    f32x4 acc2[8][2];
#pragma unroll
    for (int m = 0; m < 8; ++m) {
        acc2[m][0] = (f32x4){0.f, 0.f, 0.f, 0.f};
        acc2[m][1] = (f32x4){0.f, 0.f, 0.f, 0.f};
    }
#pragma unroll
    for (int ks = 0; ks < 12; ++ks) {
        const int j     = ks >> 2;
        const int c0    = (ks & 3) << 5;
        const int shift = (2 - j) * DIL;
#pragma unroll
        for (int m = 0; m < 8; ++m) {
            f16x8 af = *(const f16x8*)&buf[m * 16 + shift + l15][c0 + kg * 8];
            acc2[m][0] = __builtin_amdgcn_mfma_f32_16x16x32_f16(af, w2[ks][0], acc2[m][0], 0, 0, 0);
            acc2[m][1] = __builtin_amdgcn_mfma_f32_16x16x32_f16(af, w2[ks][1], acc2[m][1], 0, 0, 0);
        }
    }

    // ---- epilogue: bias2 + relu, + residual (f32 x from global), relu, store
#pragma unroll
    for (int m = 0; m < 8; ++m) {
#pragma unroll
        for (int nn = 0; nn < 2; ++nn) {
            const float bv = nn ? bv2_1 : bv2_0;
            const int f = nc + nn * 16 + l15;
#pragma unroll
            for (int i = 0; i < 4; ++i) {
                const int r = m * 16 + kg * 4 + i;
                const int t = t0 + r;
                const int nv = 1 + (t < TLEN - DIL) + (t < TLEN - 2 * DIL);
                float v = acc2[m][nn][i] + (float)nv * bv;
                v = fmaxf(v, 0.0f);
                const size_t gi = ((size_t)b * TLEN + t) * CH + f;
                v = v + x[gi];
                v = fmaxf(v, 0.0f);
                out[gi] = v;
            }
        }
    }
}

// ---------------------------------------------------------------------------
extern "C" void kernel_launch(void* const* d_in, const int* in_sizes, int n_in,
                              void* d_out, int out_size, void* d_ws, size_t ws_size,
                              hipStream_t stream) {
    const float* x  = (const float*)d_in[0];
    const float* W1 = (const float*)d_in[1];
    const float* b1 = (const float*)d_in[2];
    const float* W2 = (const float*)d_in[3];
    const float* b2 = (const float*)d_in[4];
    float* out = (float*)d_out;

    // workspace: Wt1 (3*128*128 f16) | Wt2
    _Float16* Wt1 = (_Float16*)d_ws;
    _Float16* Wt2 = Wt1 + KW * CH * CH;

    prep_weights_kernel<<<(2 * KW * CH * CH + 255) / 256, 256, 0, stream>>>(W1, W2, Wt1, Wt2);

    const int grid = BATCH * (TLEN / BM);   // 1024 blocks
    fused_deconv_kernel<<<grid, 256, 0, stream>>>(x, Wt1, b1, Wt2, b2, out);
}